// Round 8
// baseline (423.723 us; speedup 1.0000x reference)
//
#include <hip/hip_runtime.h>
#include <hip/hip_bf16.h>
#include <hip/hip_fp16.h>
#include <math.h>

#define FF 256      // feature dim (K)
#define UU 256      // units (N)
#define DD 128      // mean/var split
#define BMG 64      // gemm row tile
#define BKG 32      // gemm k tile
#define ALD 40      // LDS row stride in bf16 elems (80B: 16B-aligned; with lane<->row
                    // staging map all ds ops are bank-conflict-free: starts 20r mod 32)

typedef short short8 __attribute__((ext_vector_type(8)));
typedef float f32x4  __attribute__((ext_vector_type(4)));

// round-to-nearest-even fp32 -> bf16 bits (finite inputs)
__device__ __forceinline__ unsigned short f2bf(float x) {
    unsigned int u = __float_as_uint(x);
    return (unsigned short)((u + 0x7fffu + ((u >> 16) & 1u)) >> 16);
}
__device__ __forceinline__ float bf2f(unsigned short b) {
    return __uint_as_float(((unsigned int)b) << 16);
}

// ---------------------------------------------------------------------------
// Kernel 0: split B into bf16 hi/lo, TRANSPOSED: Bt[n][k]
// ---------------------------------------------------------------------------
__global__ __launch_bounds__(256)
void prep_b_kernel(const float* __restrict__ B,
                   unsigned short* __restrict__ Bth,
                   unsigned short* __restrict__ Btl) {
    __shared__ float tile[64][65];
    const int t  = threadIdx.x;
    const int k0 = (blockIdx.x & 3) * 64;
    const int n0 = (blockIdx.x >> 2) * 64;
    #pragma unroll
    for (int i = 0; i < 16; ++i) {
        int idx = t + 256 * i;
        int kk = idx >> 6, nn = idx & 63;
        tile[kk][nn] = B[(size_t)(k0 + kk) * UU + n0 + nn];
    }
    __syncthreads();
    #pragma unroll
    for (int i = 0; i < 16; ++i) {
        int idx = t + 256 * i;
        int nn = idx >> 6, kk = idx & 63;
        float b = tile[kk][nn];
        unsigned short hb = f2bf(b);
        unsigned short lb = f2bf(b - bf2f(hb));
        Bth[(size_t)(n0 + nn) * FF + k0 + kk] = hb;
        Btl[(size_t)(n0 + nn) * FF + k0 + kk] = lb;
    }
}

// ---------------------------------------------------------------------------
// Kernel 1: bf16x3 MFMA GEMM + fused epilogue -> xmv fp16, kl partials.
// Prefetch kt+1 into regs during MFMA (round-7 win, kept).
// NEW: lane<->row staging map (conflict-free ds_writes) + truncation split.
// ---------------------------------------------------------------------------
__global__ __launch_bounds__(256, 2)
void gemm_mfma_kernel(const float* __restrict__ A,
                      const unsigned short* __restrict__ Bth,
                      const unsigned short* __restrict__ Btl,
                      __half* __restrict__ xmv,
                      float* __restrict__ klpart,
                      int n) {
    __shared__ unsigned short Ah[BMG * ALD], Al[BMG * ALD];
    __shared__ unsigned short Bh[UU * ALD],  Bl[UU * ALD];
    __shared__ float kls[4];

    const int t    = threadIdx.x;
    const int lane = t & 63;
    const int w    = t >> 6;
    const int l15  = lane & 15;
    const int lk   = (lane >> 4) * 8;
    const int r0   = blockIdx.x * BMG;

    f32x4 acc[4][4];
    #pragma unroll
    for (int m = 0; m < 4; ++m)
        #pragma unroll
        for (int j = 0; j < 4; ++j)
            acc[m][j] = (f32x4){0.f, 0.f, 0.f, 0.f};

    // staging maps (lane <-> row: quarter-wave rows consecutive -> banks 20r cover all 32)
    const int arow  = t & 63;            // A row = lane
    const int akseg = (t >> 6) * 8;      // k-chunk from wave id
    int garow = r0 + arow; if (garow >= n) garow = n - 1;
    const float* aptr = A + (size_t)garow * FF + akseg;
    // B: thread t owns row t, all 4 k-chunks

    // prefetch regs for current kt
    float4 pa0, pa1;
    short8 pbh[4], pbl[4];

    pa0 = *(const float4*)(aptr + 0);
    pa1 = *(const float4*)(aptr + 4);
    #pragma unroll
    for (int p = 0; p < 4; ++p) {
        pbh[p] = *(const short8*)(Bth + (size_t)t * FF + 0 + p * 8);
        pbl[p] = *(const short8*)(Btl + (size_t)t * FF + 0 + p * 8);
    }

    for (int kt = 0; kt < FF; kt += BKG) {
        // ---- write staged regs -> LDS (truncation split: hi=chop, lo exact-f32 then RNE) ----
        {
            float av[8] = {pa0.x, pa0.y, pa0.z, pa0.w, pa1.x, pa1.y, pa1.z, pa1.w};
            short8 hv, lv;
            #pragma unroll
            for (int i = 0; i < 8; ++i) {
                unsigned short hb = (unsigned short)(__float_as_uint(av[i]) >> 16);
                float lo = av[i] - bf2f(hb);     // exact in f32
                hv[i] = (short)hb;
                lv[i] = (short)f2bf(lo);
            }
            *(short8*)(Ah + arow * ALD + akseg) = hv;
            *(short8*)(Al + arow * ALD + akseg) = lv;
            #pragma unroll
            for (int p = 0; p < 4; ++p) {
                *(short8*)(Bh + t * ALD + p * 8) = pbh[p];
                *(short8*)(Bl + t * ALD + p * 8) = pbl[p];
            }
        }
        __syncthreads();

        // ---- issue kt+1 global loads (overlap with MFMA below) ----
        const int kt2 = kt + BKG;
        if (kt2 < FF) {
            pa0 = *(const float4*)(aptr + kt2);
            pa1 = *(const float4*)(aptr + kt2 + 4);
            #pragma unroll
            for (int p = 0; p < 4; ++p) {
                pbh[p] = *(const short8*)(Bth + (size_t)t * FF + kt2 + p * 8);
                pbl[p] = *(const short8*)(Btl + (size_t)t * FF + kt2 + p * 8);
            }
        }

        // ---- fragments + MFMA ----
        short8 fah[4], fal[4], fbh[4], fbl[4];
        #pragma unroll
        for (int m = 0; m < 4; ++m) {
            int row = 16 * m + l15;
            fah[m] = *(const short8*)(Ah + row * ALD + lk);
            fal[m] = *(const short8*)(Al + row * ALD + lk);
        }
        #pragma unroll
        for (int j = 0; j < 4; ++j) {
            int nn = (j < 2) ? (32 * w + 16 * j + l15)
                             : (DD + 32 * w + 16 * (j - 2) + l15);
            fbh[j] = *(const short8*)(Bh + nn * ALD + lk);
            fbl[j] = *(const short8*)(Bl + nn * ALD + lk);
        }
        #pragma unroll
        for (int m = 0; m < 4; ++m)
            #pragma unroll
            for (int j = 0; j < 4; ++j) {
                acc[m][j] = __builtin_amdgcn_mfma_f32_16x16x32_bf16(fah[m], fbh[j], acc[m][j], 0, 0, 0);
                acc[m][j] = __builtin_amdgcn_mfma_f32_16x16x32_bf16(fal[m], fbh[j], acc[m][j], 0, 0, 0);
                acc[m][j] = __builtin_amdgcn_mfma_f32_16x16x32_bf16(fah[m], fbl[j], acc[m][j], 0, 0, 0);
            }
        __syncthreads();
    }

    // ---- fused epilogue: D row = (lane>>4)*4 + reg, col = l15 ----
    float klsum = 0.f;
    const int rbase = (lane >> 4) * 4;
    #pragma unroll
    for (int m = 0; m < 4; ++m)
        #pragma unroll
        for (int reg = 0; reg < 4; ++reg) {
            const int gr = r0 + 16 * m + rbase + reg;
            if (gr < n) {
                #pragma unroll
                for (int j = 0; j < 2; ++j) {
                    float h1 = acc[m][j][reg];
                    float h2 = acc[m][j + 2][reg];
                    float mm = h1 > 0.f ? h1 : expm1f(h1);
                    float vv = h2 > 0.f ? h2 : 0.f;
                    klsum += mm * mm + vv - logf(1e-8f + vv) - 1.f;
                    float att = expf(-vv);
                    const int cm = 32 * w + 16 * j + l15;
                    xmv[(size_t)gr * UU + cm]      = __float2half(mm * att);
                    xmv[(size_t)gr * UU + cm + DD] = __float2half(vv * att * att);
                }
            }
        }

    #pragma unroll
    for (int off = 32; off > 0; off >>= 1)
        klsum += __shfl_down(klsum, off, 64);
    if (lane == 0) kls[w] = klsum;
    __syncthreads();
    if (t == 0) klpart[blockIdx.x] = kls[0] + kls[1] + kls[2] + kls[3];
}

// ---------------------------------------------------------------------------
// Kernel 2a: rowptr[r] = lower_bound(row, r), r in [0, n]
// ---------------------------------------------------------------------------
__global__ __launch_bounds__(256)
void rowptr_kernel(const int* __restrict__ rowi, int* __restrict__ rowptr,
                   int n, int e) {
    const int r = blockIdx.x * 256 + threadIdx.x;
    if (r > n) return;
    int lo = 0, hi = e;
    while (lo < hi) { int mid = (lo + hi) >> 1; if (rowi[mid] < r) lo = mid + 1; else hi = mid; }
    rowptr[r] = lo;
}

// ---------------------------------------------------------------------------
// Kernel 2b: SpMM (round-6 structure reverted: one wave per row, uniform
// NT metadata loads) + 8-deep gather ILP.
// ---------------------------------------------------------------------------
__device__ __forceinline__ void fma4h(float4& a, float w, uint2 v) {
    __half2 p = *(__half2*)&v.x, q = *(__half2*)&v.y;
    float2 pf = __half22float2(p), qf = __half22float2(q);
    a.x = fmaf(w, pf.x, a.x); a.y = fmaf(w, pf.y, a.y);
    a.z = fmaf(w, qf.x, a.z); a.w = fmaf(w, qf.y, a.w);
}

__global__ __launch_bounds__(256)
void spmm_kernel(const int* __restrict__ rowptr,
                 const int* __restrict__ coli,
                 const float* __restrict__ w1,
                 const float* __restrict__ w2,
                 const __half* __restrict__ xmv,
                 float* __restrict__ out,
                 int n) {
    const int lane = threadIdx.x & 63;
    const int wv   = threadIdx.x >> 6;
    const int r    = blockIdx.x * 4 + wv;
    if (r >= n) return;

    const uint2* __restrict__ x2 = (const uint2*)xmv;   // 4 halfs / lane
    const int lb = rowptr[r];
    const int ub = rowptr[r + 1];
    const float* __restrict__ wsrc = (lane < 32) ? w1 : w2;

    float4 a0 = make_float4(0.f,0.f,0.f,0.f), a1 = a0, a2 = a0, a3 = a0;
    int e = lb;
    for (; e + 8 <= ub; e += 8) {
        const int c0 = __builtin_nontemporal_load(coli + e);
        const int c1 = __builtin_nontemporal_load(coli + e + 1);
        const int c2 = __builtin_nontemporal_load(coli + e + 2);
        const int c3 = __builtin_nontemporal_load(coli + e + 3);
        const int c4 = __builtin_nontemporal_load(coli + e + 4);
        const int c5 = __builtin_nontemporal_load(coli + e + 5);
        const int c6 = __builtin_nontemporal_load(coli + e + 6);
        const int c7 = __builtin_nontemporal_load(coli + e + 7);
        const float w0 = __builtin_nontemporal_load(wsrc + e);
        const float w1v = __builtin_nontemporal_load(wsrc + e + 1);
        const float w2v = __builtin_nontemporal_load(wsrc + e + 2);
        const float w3v = __builtin_nontemporal_load(wsrc + e + 3);
        const float w4v = __builtin_nontemporal_load(wsrc + e + 4);
        const float w5v = __builtin_nontemporal_load(wsrc + e + 5);
        const float w6v = __builtin_nontemporal_load(wsrc + e + 6);
        const float w7v = __builtin_nontemporal_load(wsrc + e + 7);
        const uint2 v0 = x2[(size_t)c0 * 64 + lane];
        const uint2 v1 = x2[(size_t)c1 * 64 + lane];
        const uint2 v2 = x2[(size_t)c2 * 64 + lane];
        const uint2 v3 = x2[(size_t)c3 * 64 + lane];
        const uint2 v4 = x2[(size_t)c4 * 64 + lane];
        const uint2 v5 = x2[(size_t)c5 * 64 + lane];
        const uint2 v6 = x2[(size_t)c6 * 64 + lane];
        const uint2 v7 = x2[(size_t)c7 * 64 + lane];
        fma4h(a0, w0, v0);  fma4h(a1, w1v, v1);
        fma4h(a2, w2v, v2); fma4h(a3, w3v, v3);
        fma4h(a0, w4v, v4); fma4h(a1, w5v, v5);
        fma4h(a2, w6v, v6); fma4h(a3, w7v, v7);
    }
    for (; e + 4 <= ub; e += 4) {
        const int c0 = __builtin_nontemporal_load(coli + e);
        const int c1 = __builtin_nontemporal_load(coli + e + 1);
        const int c2 = __builtin_nontemporal_load(coli + e + 2);
        const int c3 = __builtin_nontemporal_load(coli + e + 3);
        const float w0 = __builtin_nontemporal_load(wsrc + e);
        const float w1v = __builtin_nontemporal_load(wsrc + e + 1);
        const float w2v = __builtin_nontemporal_load(wsrc + e + 2);
        const float w3v = __builtin_nontemporal_load(wsrc + e + 3);
        const uint2 v0 = x2[(size_t)c0 * 64 + lane];
        const uint2 v1 = x2[(size_t)c1 * 64 + lane];
        const uint2 v2 = x2[(size_t)c2 * 64 + lane];
        const uint2 v3 = x2[(size_t)c3 * 64 + lane];
        fma4h(a0, w0, v0);  fma4h(a1, w1v, v1);
        fma4h(a2, w2v, v2); fma4h(a3, w3v, v3);
    }
    for (; e < ub; ++e) {
        const int c = coli[e];
        const float w = wsrc[e];
        fma4h(a0, w, x2[(size_t)c * 64 + lane]);
    }
    f32x4 res;
    res[0] = (a0.x + a1.x) + (a2.x + a3.x);
    res[1] = (a0.y + a1.y) + (a2.y + a3.y);
    res[2] = (a0.z + a1.z) + (a2.z + a3.z);
    res[3] = (a0.w + a1.w) + (a2.w + a3.w);
    __builtin_nontemporal_store(res, (f32x4*)out + (size_t)r * 64 + lane);
}

// ---------------------------------------------------------------------------
// Kernel 3: reduce kl partials
// ---------------------------------------------------------------------------
__global__ __launch_bounds__(256)
void klreduce_kernel(const float* __restrict__ klpart, int nparts,
                     float* __restrict__ dst) {
    __shared__ float tmp[4];
    const int t = threadIdx.x;
    float s = 0.f;
    for (int i = t; i < nparts; i += 256) s += klpart[i];
    #pragma unroll
    for (int off = 32; off > 0; off >>= 1)
        s += __shfl_down(s, off, 64);
    if ((t & 63) == 0) tmp[t >> 6] = s;
    __syncthreads();
    if (t == 0) dst[0] = (0.5f / (float)DD) * (tmp[0] + tmp[1] + tmp[2] + tmp[3]);
}

// ---------------------------------------------------------------------------
extern "C" void kernel_launch(void* const* d_in, const int* in_sizes, int n_in,
                              void* d_out, int out_size, void* d_ws, size_t ws_size,
                              hipStream_t stream) {
    const float* features = (const float*)d_in[0];
    const float* kernelW  = (const float*)d_in[1];
    const int*   row      = (const int*)d_in[2];
    const int*   col      = (const int*)d_in[3];
    const float* a1       = (const float*)d_in[4];
    const float* a2       = (const float*)d_in[5];
    float*       out      = (float*)d_out;

    const int n = in_sizes[0] / FF;     // 100000
    const int e = in_sizes[2];          // 1600000

    // ws layout
    __half*         xmv    = (__half*)d_ws;                         // n*256 fp16
    unsigned short* Bth    = (unsigned short*)(xmv + (size_t)n * UU);
    unsigned short* Btl    = Bth + (size_t)FF * UU;
    int*            rowptr = (int*)(Btl + (size_t)FF * UU);         // n+1 ints
    float*          klpart = (float*)(rowptr + n + 2);

    const int nblocks = (n + BMG - 1) / BMG;          // 1563

    prep_b_kernel<<<16, 256, 0, stream>>>(kernelW, Bth, Btl);
    gemm_mfma_kernel<<<nblocks, 256, 0, stream>>>(features, Bth, Btl, xmv, klpart, n);
    rowptr_kernel<<<(n + 256) / 256, 256, 0, stream>>>(row, rowptr, n, e);
    spmm_kernel<<<(n + 3) / 4, 256, 0, stream>>>(rowptr, col, a1, a2, xmv, out, n);
    klreduce_kernel<<<1, 256, 0, stream>>>(klpart, nblocks, out + (size_t)n * UU);
}